// Round 10
// baseline (438.124 us; speedup 1.0000x reference)
//
#include <hip/hip_runtime.h>

#define NNODES 50000
#define NEDGES 800000
#define NFEAT 512
#define NHID 64
#define NCLASSES 40
#define NLAYERS 10
#define ALPHA 0.8f
#define HALF 25000   // src block boundary for cache-blocked SpMM

typedef unsigned int uint32;
typedef unsigned short bf16_t;
typedef __attribute__((ext_vector_type(8))) short s16x8;
typedef __attribute__((ext_vector_type(4))) float f32x4;
typedef __attribute__((ext_vector_type(4))) unsigned int u32x4;

__device__ __forceinline__ float bflo(uint32 u) { return __uint_as_float(u << 16); }
__device__ __forceinline__ float bfhi(uint32 u) { return __uint_as_float(u & 0xFFFF0000u); }
__device__ __forceinline__ bf16_t f2bf(float f) {
    uint32 u = __float_as_uint(f);
    u += 0x7FFFu + ((u >> 16) & 1u);      // round-to-nearest-even
    return (bf16_t)(u >> 16);
}

// ---------------- CSR build (once per call), src-blocked rows ----------------

__global__ void zero_counts_kernel(int* __restrict__ counts) {
    int i = blockIdx.x * blockDim.x + threadIdx.x;
    if (i < 2 * NNODES) counts[i] = 0;
}

// countsA[d] = edges with src<HALF, countsB[d] = rest
__global__ void hist_kernel(const int* __restrict__ src, const int* __restrict__ dst,
                            int* __restrict__ countsA, int* __restrict__ countsB) {
    int e = blockIdx.x * blockDim.x + threadIdx.x;
    if (e >= NEDGES) return;
    int d = dst[e];
    if (src[e] < HALF) atomicAdd(&countsA[d], 1);
    else               atomicAdd(&countsB[d], 1);
}

__global__ void scan1_kernel(const int* __restrict__ countsA, const int* __restrict__ countsB,
                             int* __restrict__ row_ptr, int* __restrict__ bsum) {
    __shared__ int sd[1024];
    int tid = threadIdx.x;
    int i = blockIdx.x * 1024 + tid;
    int v = (i < NNODES) ? (countsA[i] + countsB[i]) : 0;
    sd[tid] = v;
    __syncthreads();
    for (int off = 1; off < 1024; off <<= 1) {
        int t = (tid >= off) ? sd[tid - off] : 0;
        __syncthreads();
        sd[tid] += t;
        __syncthreads();
    }
    if (i < NNODES) row_ptr[i] = sd[tid] - v;
    if (tid == 1023) bsum[blockIdx.x] = sd[1023];
}

__global__ void scan2_kernel(const int* __restrict__ bsum, int* __restrict__ boff) {
    int tid = threadIdx.x;
    const int NB = (NNODES + 1023) / 1024;   // 49
    int v0 = (tid < NB) ? bsum[tid] : 0;
    int v = v0;
#pragma unroll
    for (int off = 1; off < 64; off <<= 1) {
        int t = __shfl_up(v, off);
        if (tid >= off) v += t;
    }
    if (tid < NB) boff[tid] = v - v0;
    if (tid == NB - 1) boff[NB] = v;
}

__global__ void scan3_kernel(const int* __restrict__ boff, const int* __restrict__ countsA,
                             int* __restrict__ row_ptr, int* __restrict__ split,
                             int* __restrict__ cursorA, int* __restrict__ cursorB) {
    int i = blockIdx.x * blockDim.x + threadIdx.x;
    if (i < NNODES) {
        int rp = row_ptr[i] + boff[i >> 10];
        int sp = rp + countsA[i];
        row_ptr[i] = rp;
        split[i] = sp;
        cursorA[i] = rp;
        cursorB[i] = sp;
    } else if (i == NNODES) {
        row_ptr[NNODES] = boff[(NNODES + 1023) / 1024];
    }
}

// packed edge: low 16 = src (fits: 50000 < 65536), high 16 = bf16(ALPHA*w)
__global__ void csr_scatter_kernel(const int* __restrict__ src, const int* __restrict__ dst,
                                   const float* __restrict__ ew,
                                   int* __restrict__ cursorA, int* __restrict__ cursorB,
                                   uint32* __restrict__ edata) {
    int e = blockIdx.x * blockDim.x + threadIdx.x;
    if (e >= NEDGES) return;
    int d = dst[e];
    int s = src[e];
    int pos = (s < HALF) ? atomicAdd(&cursorA[d], 1) : atomicAdd(&cursorB[d], 1);
    edata[pos] = (uint32)s | ((uint32)f2bf(ALPHA * ew[e]) << 16);
}

// ---------------- linear_in via MFMA ----------------

__global__ void prep_w_kernel(const float* __restrict__ W, bf16_t* __restrict__ wfrag) {
    int i = blockIdx.x * blockDim.x + threadIdx.x;
    if (i >= NFEAT * NHID) return;
    int k = i >> 6, n = i & 63;
    int kb = k >> 5, ko = k & 31, hi = ko >> 3, j = ko & 7;
    int nb = n >> 4, lo = n & 15;
    int lane = hi * 16 + lo;
    wfrag[(size_t)((kb * 4 + nb) * 64 + lane) * 8 + j] = f2bf(W[(size_t)k * NHID + n]);
}

// h0 = bf16(x @ W_in + b_in), unified [node][64] layout. One wave per 16 nodes.
__global__ __launch_bounds__(256) void linear_in_kernel(
        const float* __restrict__ x, const bf16_t* __restrict__ wfrag,
        const float* __restrict__ b, bf16_t* __restrict__ h0) {
    __shared__ u32x4 wl4[4096];    // 64 KB
    const bf16_t* wl = (const bf16_t*)wl4;
    int tid = threadIdx.x;
    for (int i = tid; i < 4096; i += 256)
        wl4[i] = ((const u32x4*)wfrag)[i];
    __syncthreads();

    int wid = (blockIdx.x * 256 + tid) >> 6;
    if (wid >= NNODES / 16) return;        // 3125 waves
    int lane = tid & 63;
    int node0 = wid * 16;
    int row = node0 + (lane & 15);
    int khi = (lane >> 4) << 3;            // 0,8,16,24

    f32x4 acc[4];
#pragma unroll
    for (int nb = 0; nb < 4; ++nb) acc[nb] = (f32x4){0.f, 0.f, 0.f, 0.f};

    const float* xr = x + (size_t)row * NFEAT + khi;
#pragma unroll 4
    for (int kb = 0; kb < 16; ++kb) {
        float4 xa = *(const float4*)(xr);
        float4 xb = *(const float4*)(xr + 4);
        xr += 32;
        s16x8 a;
        a[0] = (short)f2bf(xa.x); a[1] = (short)f2bf(xa.y);
        a[2] = (short)f2bf(xa.z); a[3] = (short)f2bf(xa.w);
        a[4] = (short)f2bf(xb.x); a[5] = (short)f2bf(xb.y);
        a[6] = (short)f2bf(xb.z); a[7] = (short)f2bf(xb.w);
#pragma unroll
        for (int nb = 0; nb < 4; ++nb) {
            s16x8 bb = *(const s16x8*)(&wl[(size_t)((kb * 4 + nb) * 64 + lane) * 8]);
            acc[nb] = __builtin_amdgcn_mfma_f32_16x16x32_bf16(a, bb, acc[nb], 0, 0, 0);
        }
    }

    int chi = lane >> 4;
#pragma unroll
    for (int nb = 0; nb < 4; ++nb) {
        int col = nb * 16 + (lane & 15);
        float bias = b[col];
#pragma unroll
        for (int r = 0; r < 4; ++r) {
            int n = node0 + chi * 4 + r;
            h0[(size_t)n * NHID + col] = f2bf(acc[nb][r] + bias);
        }
    }
}

// ---------------- SpMM: src-blocked two-pass ----------------

__device__ __forceinline__ void acc_edge(float* acc, u32x4 g, float wgt) {
    acc[0] = fmaf(wgt, bflo(g[0]), acc[0]);
    acc[1] = fmaf(wgt, bfhi(g[0]), acc[1]);
    acc[2] = fmaf(wgt, bflo(g[1]), acc[2]);
    acc[3] = fmaf(wgt, bfhi(g[1]), acc[3]);
    acc[4] = fmaf(wgt, bflo(g[2]), acc[4]);
    acc[5] = fmaf(wgt, bfhi(g[2]), acc[5]);
    acc[6] = fmaf(wgt, bflo(g[3]), acc[6]);
    acc[7] = fmaf(wgt, bfhi(g[3]), acc[7]);
}

// Pass FIRST=1: h_next = 0.2*h0 + sum over A-edges (src<HALF).
// Pass FIRST=0: h_next += sum over B-edges (src>=HALF).
// Gather working set per pass = 3.2 MB (fits every XCD L2). Streams are
// nontemporal so they don't evict the gather-resident block.
// 8 nodes/wave, 8 lanes x 16 B per node, 2 edges in flight.
template <int FIRST>
__global__ __launch_bounds__(256) void spmm_pass_kernel(
        const uint32* __restrict__ edata, const int* __restrict__ row_ptr,
        const int* __restrict__ split,
        const bf16_t* __restrict__ h_cur, const bf16_t* __restrict__ h0,
        bf16_t* __restrict__ h_next) {
    int gid = blockIdx.x * blockDim.x + threadIdx.x;
    int wave = gid >> 6;
    int lane = threadIdx.x & 63;
    int grp = lane >> 3;            // 0..7
    int fl = (lane & 7) << 3;       // feature base (8 bf16 = 16 B)
    int node = wave * 8 + grp;
    int beg = 0, deg = 0;
    if (node < NNODES) {
        beg = FIRST ? row_ptr[node] : split[node];
        int end = FIRST ? split[node] : row_ptr[node + 1];
        deg = end - beg;
    }
    int steps = deg;
    steps = max(steps, __shfl_xor(steps, 8));
    steps = max(steps, __shfl_xor(steps, 16));
    steps = max(steps, __shfl_xor(steps, 32));

    float acc[8];
#pragma unroll
    for (int j = 0; j < 8; ++j) acc[j] = 0.f;

    int t = 0;
    for (; t + 1 < steps; t += 2) {
        bool v0 = (t < deg), v1 = (t + 1 < deg);
        uint32 e0 = __builtin_nontemporal_load(edata + (v0 ? (beg + t) : 0));
        uint32 e1 = __builtin_nontemporal_load(edata + (v1 ? (beg + t + 1) : 0));
        float w0 = v0 ? bfhi(e0) : 0.f;
        float w1 = v1 ? bfhi(e1) : 0.f;
        u32x4 g0 = *(const u32x4*)(h_cur + ((size_t)(e0 & 0xFFFFu) << 6) + fl);
        u32x4 g1 = *(const u32x4*)(h_cur + ((size_t)(e1 & 0xFFFFu) << 6) + fl);
        acc_edge(acc, g0, w0);
        acc_edge(acc, g1, w1);
    }
    if (t < steps) {
        bool v0 = (t < deg);
        uint32 e0 = __builtin_nontemporal_load(edata + (v0 ? (beg + t) : 0));
        float w0 = v0 ? bfhi(e0) : 0.f;
        u32x4 g0 = *(const u32x4*)(h_cur + ((size_t)(e0 & 0xFFFFu) << 6) + fl);
        acc_edge(acc, g0, w0);
    }

    if (node < NNODES) {
        size_t o = ((size_t)node << 6) + fl;
        float r[8];
        if (FIRST) {
            u32x4 hv = __builtin_nontemporal_load((const u32x4*)(h0 + o));
            const float s = 1.0f - ALPHA;
            r[0] = fmaf(s, bflo(hv[0]), acc[0]);
            r[1] = fmaf(s, bfhi(hv[0]), acc[1]);
            r[2] = fmaf(s, bflo(hv[1]), acc[2]);
            r[3] = fmaf(s, bfhi(hv[1]), acc[3]);
            r[4] = fmaf(s, bflo(hv[2]), acc[4]);
            r[5] = fmaf(s, bfhi(hv[2]), acc[5]);
            r[6] = fmaf(s, bflo(hv[3]), acc[6]);
            r[7] = fmaf(s, bfhi(hv[3]), acc[7]);
        } else {
            u32x4 hv = __builtin_nontemporal_load((const u32x4*)(h_next + o));
            r[0] = bflo(hv[0]) + acc[0];
            r[1] = bfhi(hv[0]) + acc[1];
            r[2] = bflo(hv[1]) + acc[2];
            r[3] = bfhi(hv[1]) + acc[3];
            r[4] = bflo(hv[2]) + acc[4];
            r[5] = bfhi(hv[2]) + acc[5];
            r[6] = bflo(hv[3]) + acc[6];
            r[7] = bfhi(hv[3]) + acc[7];
        }
        u32x4 ov;
        ov[0] = (uint32)f2bf(r[0]) | ((uint32)f2bf(r[1]) << 16);
        ov[1] = (uint32)f2bf(r[2]) | ((uint32)f2bf(r[3]) << 16);
        ov[2] = (uint32)f2bf(r[4]) | ((uint32)f2bf(r[5]) << 16);
        ov[3] = (uint32)f2bf(r[6]) | ((uint32)f2bf(r[7]) << 16);
        __builtin_nontemporal_store(ov, (u32x4*)(h_next + o));
    }
}

// ---------------- linear_out ----------------

__global__ __launch_bounds__(256) void linear_out_kernel(
        const bf16_t* __restrict__ h, const float* __restrict__ W,
        const float* __restrict__ b, float* __restrict__ out) {
    __shared__ float wsh[NHID * NCLASSES];
    __shared__ float bs[NCLASSES];
    int tid = threadIdx.x;
    for (int i = tid; i < NHID * NCLASSES; i += 256) wsh[i] = W[i];
    if (tid < NCLASSES) bs[tid] = b[tid];
    __syncthreads();
    int node = blockIdx.x * 256 + tid;
    if (node >= NNODES) return;
    float acc[NCLASSES];
#pragma unroll
    for (int c = 0; c < NCLASSES; ++c) acc[c] = bs[c];
    const bf16_t* hr = h + (size_t)node * NHID;
#pragma unroll
    for (int q = 0; q < 8; ++q) {
        u32x4 v = *(const u32x4*)(hr + q * 8);
        float hv[8];
        hv[0] = bflo(v[0]); hv[1] = bfhi(v[0]);
        hv[2] = bflo(v[1]); hv[3] = bfhi(v[1]);
        hv[4] = bflo(v[2]); hv[5] = bfhi(v[2]);
        hv[6] = bflo(v[3]); hv[7] = bfhi(v[3]);
#pragma unroll
        for (int kk = 0; kk < 8; ++kk) {
#pragma unroll
            for (int c = 0; c < NCLASSES; ++c)
                acc[c] = fmaf(hv[kk], wsh[(q * 8 + kk) * NCLASSES + c], acc[c]);
        }
    }
    float* op = out + (size_t)node * NCLASSES;
#pragma unroll
    for (int c = 0; c < NCLASSES; c += 4)
        *(float4*)(op + c) = make_float4(acc[c], acc[c + 1], acc[c + 2], acc[c + 3]);
}

extern "C" void kernel_launch(void* const* d_in, const int* in_sizes, int n_in,
                              void* d_out, int out_size, void* d_ws, size_t ws_size,
                              hipStream_t stream) {
    const float* x     = (const float*)d_in[0];
    const int*   ei    = (const int*)d_in[1];
    const float* ew    = (const float*)d_in[2];
    const float* W_in  = (const float*)d_in[3];
    const float* b_in  = (const float*)d_in[4];
    const float* W_out = (const float*)d_in[5];
    const float* b_out = (const float*)d_in[6];
    float* out = (float*)d_out;

    const int HN = NNODES * NHID;            // 3.2M elements
    bf16_t* h0 = (bf16_t*)d_ws;              // 6.4 MB each
    bf16_t* ha = h0 + HN;
    bf16_t* hb = ha + HN;
    bf16_t* wfrag = hb + HN;                 // 64 KB
    uint32* edata  = (uint32*)(wfrag + NFEAT * NHID);   // 3.2 MB packed
    int* row_ptr = (int*)(edata + NEDGES);   // NNODES+1
    int* split   = row_ptr + (NNODES + 1);
    int* cursorA = split + NNODES;
    int* cursorB = cursorA + NNODES;
    int* counts  = cursorB + NNODES;         // 2*NNODES (A then B)
    int* bsum    = counts + 2 * NNODES;
    int* boff    = bsum + 64;

    const int* src = ei;
    const int* dst = ei + NEDGES;
    int* countsA = counts;
    int* countsB = counts + NNODES;

    // ---- CSR build (src-blocked rows, packed 4B edges) ----
    zero_counts_kernel<<<(2 * NNODES + 255) / 256, 256, 0, stream>>>(counts);
    hist_kernel<<<(NEDGES + 255) / 256, 256, 0, stream>>>(src, dst, countsA, countsB);
    const int NB = (NNODES + 1023) / 1024;
    scan1_kernel<<<NB, 1024, 0, stream>>>(countsA, countsB, row_ptr, bsum);
    scan2_kernel<<<1, 64, 0, stream>>>(bsum, boff);
    scan3_kernel<<<(NNODES + 256) / 256, 256, 0, stream>>>(
        boff, countsA, row_ptr, split, cursorA, cursorB);
    csr_scatter_kernel<<<(NEDGES + 255) / 256, 256, 0, stream>>>(
        src, dst, ew, cursorA, cursorB, edata);

    // ---- h0 = bf16(x @ W_in + b_in), via MFMA ----
    prep_w_kernel<<<(NFEAT * NHID + 255) / 256, 256, 0, stream>>>(W_in, wfrag);
    const int GEMM_BLOCKS = (NNODES / 16 + 3) / 4;   // 782
    linear_in_kernel<<<GEMM_BLOCKS, 256, 0, stream>>>(x, wfrag, b_in, h0);

    // ---- 10 APPNP layers, 2 src-blocked passes each ----
    const int NWAVES = (NNODES + 7) / 8;                 // 6250
    const int SPMM_BLOCKS = (NWAVES * 64 + 255) / 256;   // 1563
    bf16_t* cur = h0;
    bf16_t* nxt = ha;
    for (int l = 0; l < NLAYERS; ++l) {
        spmm_pass_kernel<1><<<SPMM_BLOCKS, 256, 0, stream>>>(
            edata, row_ptr, split, cur, h0, nxt);
        spmm_pass_kernel<0><<<SPMM_BLOCKS, 256, 0, stream>>>(
            edata, row_ptr, split, cur, h0, nxt);
        cur = nxt;
        nxt = (cur == ha) ? hb : ha;
    }

    // ---- out = cur @ W_out + b_out ----
    linear_out_kernel<<<(NNODES + 255) / 256, 256, 0, stream>>>(cur, W_out, b_out, out);
}

// Round 11
// 304.076 us; speedup vs baseline: 1.4408x; 1.4408x over previous
//
#include <hip/hip_runtime.h>

#define NNODES 50000
#define NEDGES 800000
#define NFEAT 512
#define NHID 64
#define NCLASSES 40
#define NLAYERS 10
#define ALPHA 0.8f

typedef unsigned int uint32;
typedef unsigned short bf16_t;
typedef __attribute__((ext_vector_type(8))) short s16x8;
typedef __attribute__((ext_vector_type(4))) float f32x4;
typedef __attribute__((ext_vector_type(4))) unsigned int u32x4;

__device__ __forceinline__ float bflo(uint32 u) { return __uint_as_float(u << 16); }
__device__ __forceinline__ float bfhi(uint32 u) { return __uint_as_float(u & 0xFFFF0000u); }
__device__ __forceinline__ bf16_t f2bf(float f) {
    uint32 u = __float_as_uint(f);
    u += 0x7FFFu + ((u >> 16) & 1u);      // round-to-nearest-even
    return (bf16_t)(u >> 16);
}

// ---------------- CSR build (once per call) ----------------

__global__ void zero_counts_kernel(int* __restrict__ counts) {
    int i = blockIdx.x * blockDim.x + threadIdx.x;
    if (i < NNODES) counts[i] = 0;
}

__global__ void hist_kernel(const int* __restrict__ dst, int* __restrict__ counts) {
    int e = blockIdx.x * blockDim.x + threadIdx.x;
    if (e >= NEDGES) return;
    atomicAdd(&counts[dst[e]], 1);
}

__global__ void scan1_kernel(const int* __restrict__ counts,
                             int* __restrict__ row_ptr,
                             int* __restrict__ bsum) {
    __shared__ int sd[1024];
    int tid = threadIdx.x;
    int i = blockIdx.x * 1024 + tid;
    int v = (i < NNODES) ? counts[i] : 0;
    sd[tid] = v;
    __syncthreads();
    for (int off = 1; off < 1024; off <<= 1) {
        int t = (tid >= off) ? sd[tid - off] : 0;
        __syncthreads();
        sd[tid] += t;
        __syncthreads();
    }
    if (i < NNODES) row_ptr[i] = sd[tid] - v;
    if (tid == 1023) bsum[blockIdx.x] = sd[1023];
}

__global__ void scan2_kernel(const int* __restrict__ bsum, int* __restrict__ boff) {
    int tid = threadIdx.x;
    const int NB = (NNODES + 1023) / 1024;   // 49
    int v0 = (tid < NB) ? bsum[tid] : 0;
    int v = v0;
#pragma unroll
    for (int off = 1; off < 64; off <<= 1) {
        int t = __shfl_up(v, off);
        if (tid >= off) v += t;
    }
    if (tid < NB) boff[tid] = v - v0;
    if (tid == NB - 1) boff[NB] = v;
}

__global__ void scan3_kernel(const int* __restrict__ boff,
                             int* __restrict__ row_ptr,
                             int* __restrict__ cursor) {
    int i = blockIdx.x * blockDim.x + threadIdx.x;
    if (i < NNODES) {
        int rp = row_ptr[i] + boff[i >> 10];
        row_ptr[i] = rp;
        cursor[i] = rp;
    } else if (i == NNODES) {
        row_ptr[NNODES] = boff[(NNODES + 1023) / 1024];
    }
}

// packed edge: low 16 = src (50000 < 65536), high 16 = bf16(ALPHA*w)
__global__ void csr_scatter_kernel(const int* __restrict__ src,
                                   const int* __restrict__ dst,
                                   const float* __restrict__ ew,
                                   int* __restrict__ cursor,
                                   uint32* __restrict__ edata) {
    int e = blockIdx.x * blockDim.x + threadIdx.x;
    if (e >= NEDGES) return;
    int d = dst[e];
    int pos = atomicAdd(&cursor[d], 1);
    edata[pos] = (uint32)src[e] | ((uint32)f2bf(ALPHA * ew[e]) << 16);
}

// ---------------- linear_in via MFMA ----------------

__global__ void prep_w_kernel(const float* __restrict__ W, bf16_t* __restrict__ wfrag) {
    int i = blockIdx.x * blockDim.x + threadIdx.x;
    if (i >= NFEAT * NHID) return;
    int k = i >> 6, n = i & 63;
    int kb = k >> 5, ko = k & 31, hi = ko >> 3, j = ko & 7;
    int nb = n >> 4, lo = n & 15;
    int lane = hi * 16 + lo;
    wfrag[(size_t)((kb * 4 + nb) * 64 + lane) * 8 + j] = f2bf(W[(size_t)k * NHID + n]);
}

// h0 = bf16(x @ W_in + b_in), unified [node][64] layout. One wave per 16 nodes.
__global__ __launch_bounds__(256) void linear_in_kernel(
        const float* __restrict__ x, const bf16_t* __restrict__ wfrag,
        const float* __restrict__ b, bf16_t* __restrict__ h0) {
    __shared__ u32x4 wl4[4096];    // 64 KB
    const bf16_t* wl = (const bf16_t*)wl4;
    int tid = threadIdx.x;
    for (int i = tid; i < 4096; i += 256)
        wl4[i] = ((const u32x4*)wfrag)[i];
    __syncthreads();

    int wid = (blockIdx.x * 256 + tid) >> 6;
    if (wid >= NNODES / 16) return;        // 3125 waves
    int lane = tid & 63;
    int node0 = wid * 16;
    int row = node0 + (lane & 15);
    int khi = (lane >> 4) << 3;            // 0,8,16,24

    f32x4 acc[4];
#pragma unroll
    for (int nb = 0; nb < 4; ++nb) acc[nb] = (f32x4){0.f, 0.f, 0.f, 0.f};

    const float* xr = x + (size_t)row * NFEAT + khi;
#pragma unroll 4
    for (int kb = 0; kb < 16; ++kb) {
        float4 xa = *(const float4*)(xr);
        float4 xb = *(const float4*)(xr + 4);
        xr += 32;
        s16x8 a;
        a[0] = (short)f2bf(xa.x); a[1] = (short)f2bf(xa.y);
        a[2] = (short)f2bf(xa.z); a[3] = (short)f2bf(xa.w);
        a[4] = (short)f2bf(xb.x); a[5] = (short)f2bf(xb.y);
        a[6] = (short)f2bf(xb.z); a[7] = (short)f2bf(xb.w);
#pragma unroll
        for (int nb = 0; nb < 4; ++nb) {
            s16x8 bb = *(const s16x8*)(&wl[(size_t)((kb * 4 + nb) * 64 + lane) * 8]);
            acc[nb] = __builtin_amdgcn_mfma_f32_16x16x32_bf16(a, bb, acc[nb], 0, 0, 0);
        }
    }

    int chi = lane >> 4;
#pragma unroll
    for (int nb = 0; nb < 4; ++nb) {
        int col = nb * 16 + (lane & 15);
        float bias = b[col];
#pragma unroll
        for (int r = 0; r < 4; ++r) {
            int n = node0 + chi * 4 + r;
            h0[(size_t)n * NHID + col] = f2bf(acc[nb][r] + bias);
        }
    }
}

// ---------------- SpMM (unified rows, plain loads/stores) ----------------

__device__ __forceinline__ void acc_edge(float* acc, u32x4 g, float wgt) {
    acc[0] = fmaf(wgt, bflo(g[0]), acc[0]);
    acc[1] = fmaf(wgt, bfhi(g[0]), acc[1]);
    acc[2] = fmaf(wgt, bflo(g[1]), acc[2]);
    acc[3] = fmaf(wgt, bfhi(g[1]), acc[3]);
    acc[4] = fmaf(wgt, bflo(g[2]), acc[4]);
    acc[5] = fmaf(wgt, bfhi(g[2]), acc[5]);
    acc[6] = fmaf(wgt, bflo(g[3]), acc[6]);
    acc[7] = fmaf(wgt, bfhi(g[3]), acc[7]);
}

// 8 nodes/wave, 8 lanes x uint4 (8 bf16 feats) per node, 4 edges in flight.
__global__ __launch_bounds__(256) void spmm_pull_kernel(
        const uint32* __restrict__ edata, const int* __restrict__ row_ptr,
        const bf16_t* __restrict__ h_cur, const bf16_t* __restrict__ h0,
        bf16_t* __restrict__ h_next) {
    int gid = blockIdx.x * blockDim.x + threadIdx.x;
    int wave = gid >> 6;
    int lane = threadIdx.x & 63;
    int grp = lane >> 3;            // 0..7
    int fl = (lane & 7) << 3;       // feature base (8 bf16 = 16 B)
    int node = wave * 8 + grp;
    int beg = 0, deg = 0;
    if (node < NNODES) {
        beg = row_ptr[node];
        deg = row_ptr[node + 1] - beg;
    }
    int steps = deg;
    steps = max(steps, __shfl_xor(steps, 8));
    steps = max(steps, __shfl_xor(steps, 16));
    steps = max(steps, __shfl_xor(steps, 32));

    float acc[8];
#pragma unroll
    for (int j = 0; j < 8; ++j) acc[j] = 0.f;

    int t = 0;
    for (; t + 3 < steps; t += 4) {
        bool v0 = (t < deg), v1 = (t + 1 < deg), v2 = (t + 2 < deg), v3 = (t + 3 < deg);
        uint32 e0 = edata[v0 ? (beg + t) : 0];
        uint32 e1 = edata[v1 ? (beg + t + 1) : 0];
        uint32 e2 = edata[v2 ? (beg + t + 2) : 0];
        uint32 e3 = edata[v3 ? (beg + t + 3) : 0];
        float w0 = v0 ? bfhi(e0) : 0.f;
        float w1 = v1 ? bfhi(e1) : 0.f;
        float w2 = v2 ? bfhi(e2) : 0.f;
        float w3 = v3 ? bfhi(e3) : 0.f;
        u32x4 g0 = *(const u32x4*)(h_cur + ((size_t)(e0 & 0xFFFFu) << 6) + fl);
        u32x4 g1 = *(const u32x4*)(h_cur + ((size_t)(e1 & 0xFFFFu) << 6) + fl);
        u32x4 g2 = *(const u32x4*)(h_cur + ((size_t)(e2 & 0xFFFFu) << 6) + fl);
        u32x4 g3 = *(const u32x4*)(h_cur + ((size_t)(e3 & 0xFFFFu) << 6) + fl);
        acc_edge(acc, g0, w0);
        acc_edge(acc, g1, w1);
        acc_edge(acc, g2, w2);
        acc_edge(acc, g3, w3);
    }
    for (; t < steps; ++t) {
        bool v0 = (t < deg);
        uint32 e0 = edata[v0 ? (beg + t) : 0];
        float w0 = v0 ? bfhi(e0) : 0.f;
        u32x4 g0 = *(const u32x4*)(h_cur + ((size_t)(e0 & 0xFFFFu) << 6) + fl);
        acc_edge(acc, g0, w0);
    }

    if (node < NNODES) {
        size_t o = ((size_t)node << 6) + fl;
        u32x4 hv = *(const u32x4*)(h0 + o);
        const float s = 1.0f - ALPHA;
        float r[8];
        r[0] = fmaf(s, bflo(hv[0]), acc[0]);
        r[1] = fmaf(s, bfhi(hv[0]), acc[1]);
        r[2] = fmaf(s, bflo(hv[1]), acc[2]);
        r[3] = fmaf(s, bfhi(hv[1]), acc[3]);
        r[4] = fmaf(s, bflo(hv[2]), acc[4]);
        r[5] = fmaf(s, bfhi(hv[2]), acc[5]);
        r[6] = fmaf(s, bflo(hv[3]), acc[6]);
        r[7] = fmaf(s, bfhi(hv[3]), acc[7]);
        u32x4 ov;
        ov[0] = (uint32)f2bf(r[0]) | ((uint32)f2bf(r[1]) << 16);
        ov[1] = (uint32)f2bf(r[2]) | ((uint32)f2bf(r[3]) << 16);
        ov[2] = (uint32)f2bf(r[4]) | ((uint32)f2bf(r[5]) << 16);
        ov[3] = (uint32)f2bf(r[6]) | ((uint32)f2bf(r[7]) << 16);
        *(u32x4*)(h_next + o) = ov;
    }
}

// ---------------- linear_out ----------------

__global__ __launch_bounds__(256) void linear_out_kernel(
        const bf16_t* __restrict__ h, const float* __restrict__ W,
        const float* __restrict__ b, float* __restrict__ out) {
    __shared__ float wsh[NHID * NCLASSES];
    __shared__ float bs[NCLASSES];
    int tid = threadIdx.x;
    for (int i = tid; i < NHID * NCLASSES; i += 256) wsh[i] = W[i];
    if (tid < NCLASSES) bs[tid] = b[tid];
    __syncthreads();
    int node = blockIdx.x * 256 + tid;
    if (node >= NNODES) return;
    float acc[NCLASSES];
#pragma unroll
    for (int c = 0; c < NCLASSES; ++c) acc[c] = bs[c];
    const bf16_t* hr = h + (size_t)node * NHID;
#pragma unroll
    for (int q = 0; q < 8; ++q) {
        u32x4 v = *(const u32x4*)(hr + q * 8);
        float hv[8];
        hv[0] = bflo(v[0]); hv[1] = bfhi(v[0]);
        hv[2] = bflo(v[1]); hv[3] = bfhi(v[1]);
        hv[4] = bflo(v[2]); hv[5] = bfhi(v[2]);
        hv[6] = bflo(v[3]); hv[7] = bfhi(v[3]);
#pragma unroll
        for (int kk = 0; kk < 8; ++kk) {
#pragma unroll
            for (int c = 0; c < NCLASSES; ++c)
                acc[c] = fmaf(hv[kk], wsh[(q * 8 + kk) * NCLASSES + c], acc[c]);
        }
    }
    float* op = out + (size_t)node * NCLASSES;
#pragma unroll
    for (int c = 0; c < NCLASSES; c += 4)
        *(float4*)(op + c) = make_float4(acc[c], acc[c + 1], acc[c + 2], acc[c + 3]);
}

extern "C" void kernel_launch(void* const* d_in, const int* in_sizes, int n_in,
                              void* d_out, int out_size, void* d_ws, size_t ws_size,
                              hipStream_t stream) {
    const float* x     = (const float*)d_in[0];
    const int*   ei    = (const int*)d_in[1];
    const float* ew    = (const float*)d_in[2];
    const float* W_in  = (const float*)d_in[3];
    const float* b_in  = (const float*)d_in[4];
    const float* W_out = (const float*)d_in[5];
    const float* b_out = (const float*)d_in[6];
    float* out = (float*)d_out;

    const int HN = NNODES * NHID;            // 3.2M elements
    bf16_t* h0 = (bf16_t*)d_ws;              // 6.4 MB each
    bf16_t* ha = h0 + HN;
    bf16_t* hb = ha + HN;
    bf16_t* wfrag = hb + HN;                 // 64 KB
    uint32* edata  = (uint32*)(wfrag + NFEAT * NHID);   // 3.2 MB packed
    int* row_ptr = (int*)(edata + NEDGES);   // NNODES+1
    int* cursor  = row_ptr + (NNODES + 1);
    int* counts  = cursor + NNODES;
    int* bsum    = counts + NNODES;
    int* boff    = bsum + 64;

    const int* src = ei;
    const int* dst = ei + NEDGES;

    // ---- CSR build (packed 4B edges) ----
    zero_counts_kernel<<<(NNODES + 255) / 256, 256, 0, stream>>>(counts);
    hist_kernel<<<(NEDGES + 255) / 256, 256, 0, stream>>>(dst, counts);
    const int NB = (NNODES + 1023) / 1024;
    scan1_kernel<<<NB, 1024, 0, stream>>>(counts, row_ptr, bsum);
    scan2_kernel<<<1, 64, 0, stream>>>(bsum, boff);
    scan3_kernel<<<(NNODES + 256) / 256, 256, 0, stream>>>(boff, row_ptr, cursor);
    csr_scatter_kernel<<<(NEDGES + 255) / 256, 256, 0, stream>>>(src, dst, ew, cursor, edata);

    // ---- h0 = bf16(x @ W_in + b_in), via MFMA ----
    prep_w_kernel<<<(NFEAT * NHID + 255) / 256, 256, 0, stream>>>(W_in, wfrag);
    const int GEMM_BLOCKS = (NNODES / 16 + 3) / 4;   // 782
    linear_in_kernel<<<GEMM_BLOCKS, 256, 0, stream>>>(x, wfrag, b_in, h0);

    // ---- 10 APPNP layers ----
    const int NWAVES = (NNODES + 7) / 8;                 // 6250
    const int SPMM_BLOCKS = (NWAVES * 64 + 255) / 256;   // 1563
    bf16_t* cur = h0;
    bf16_t* nxt = ha;
    for (int l = 0; l < NLAYERS; ++l) {
        spmm_pull_kernel<<<SPMM_BLOCKS, 256, 0, stream>>>(edata, row_ptr, cur, h0, nxt);
        cur = nxt;
        nxt = (cur == ha) ? hb : ha;
    }

    // ---- out = cur @ W_out + b_out ----
    linear_out_kernel<<<(NNODES + 255) / 256, 256, 0, stream>>>(cur, W_out, b_out, out);
}

// Round 12
// 294.285 us; speedup vs baseline: 1.4888x; 1.0333x over previous
//
#include <hip/hip_runtime.h>

#define NNODES 50000
#define NEDGES 800000
#define NFEAT 512
#define NHID 64
#define NCLASSES 40
#define NLAYERS 10
#define ALPHA 0.8f

typedef unsigned int uint32;
typedef unsigned short bf16_t;
typedef __attribute__((ext_vector_type(8))) short s16x8;
typedef __attribute__((ext_vector_type(4))) float f32x4;
typedef __attribute__((ext_vector_type(4))) unsigned int u32x4;

__device__ __forceinline__ float bflo(uint32 u) { return __uint_as_float(u << 16); }
__device__ __forceinline__ float bfhi(uint32 u) { return __uint_as_float(u & 0xFFFF0000u); }
__device__ __forceinline__ bf16_t f2bf(float f) {
    uint32 u = __float_as_uint(f);
    u += 0x7FFFu + ((u >> 16) & 1u);      // round-to-nearest-even
    return (bf16_t)(u >> 16);
}

// ---------------- CSR build (once per call) ----------------

__global__ void hist_kernel(const int* __restrict__ dst, int* __restrict__ counts) {
    int e = blockIdx.x * blockDim.x + threadIdx.x;
    if (e >= NEDGES) return;
    atomicAdd(&counts[dst[e]], 1);
}

__global__ void scan1_kernel(const int* __restrict__ counts,
                             int* __restrict__ row_ptr,
                             int* __restrict__ bsum) {
    __shared__ int sd[1024];
    int tid = threadIdx.x;
    int i = blockIdx.x * 1024 + tid;
    int v = (i < NNODES) ? counts[i] : 0;
    sd[tid] = v;
    __syncthreads();
    for (int off = 1; off < 1024; off <<= 1) {
        int t = (tid >= off) ? sd[tid - off] : 0;
        __syncthreads();
        sd[tid] += t;
        __syncthreads();
    }
    if (i < NNODES) row_ptr[i] = sd[tid] - v;
    if (tid == 1023) bsum[blockIdx.x] = sd[1023];
}

__global__ void scan2_kernel(const int* __restrict__ bsum, int* __restrict__ boff) {
    int tid = threadIdx.x;
    const int NB = (NNODES + 1023) / 1024;   // 49
    int v0 = (tid < NB) ? bsum[tid] : 0;
    int v = v0;
#pragma unroll
    for (int off = 1; off < 64; off <<= 1) {
        int t = __shfl_up(v, off);
        if (tid >= off) v += t;
    }
    if (tid < NB) boff[tid] = v - v0;
    if (tid == NB - 1) boff[NB] = v;
}

__global__ void scan3_kernel(const int* __restrict__ boff,
                             int* __restrict__ row_ptr,
                             int* __restrict__ cursor) {
    int i = blockIdx.x * blockDim.x + threadIdx.x;
    if (i < NNODES) {
        int rp = row_ptr[i] + boff[i >> 10];
        row_ptr[i] = rp;
        cursor[i] = rp;
    } else if (i == NNODES) {
        row_ptr[NNODES] = boff[(NNODES + 1023) / 1024];
    }
}

// packed edge: low 16 = src (50000 < 65536), high 16 = bf16(ALPHA*w)
__global__ void csr_scatter_kernel(const int* __restrict__ src,
                                   const int* __restrict__ dst,
                                   const float* __restrict__ ew,
                                   int* __restrict__ cursor,
                                   uint32* __restrict__ edata) {
    int e = blockIdx.x * blockDim.x + threadIdx.x;
    if (e >= NEDGES) return;
    int d = dst[e];
    int pos = atomicAdd(&cursor[d], 1);
    edata[pos] = (uint32)src[e] | ((uint32)f2bf(ALPHA * ew[e]) << 16);
}

// ---------------- linear_in via MFMA ----------------

__global__ void prep_w_kernel(const float* __restrict__ W, bf16_t* __restrict__ wfrag) {
    int i = blockIdx.x * blockDim.x + threadIdx.x;
    if (i >= NFEAT * NHID) return;
    int k = i >> 6, n = i & 63;
    int kb = k >> 5, ko = k & 31, hi = ko >> 3, j = ko & 7;
    int nb = n >> 4, lo = n & 15;
    int lane = hi * 16 + lo;
    wfrag[(size_t)((kb * 4 + nb) * 64 + lane) * 8 + j] = f2bf(W[(size_t)k * NHID + n]);
}

// h0 = bf16(x @ W_in + b_in), unified [node][64] layout. One wave per 16 nodes.
__global__ __launch_bounds__(256) void linear_in_kernel(
        const float* __restrict__ x, const bf16_t* __restrict__ wfrag,
        const float* __restrict__ b, bf16_t* __restrict__ h0) {
    __shared__ u32x4 wl4[4096];    // 64 KB
    const bf16_t* wl = (const bf16_t*)wl4;
    int tid = threadIdx.x;
    for (int i = tid; i < 4096; i += 256)
        wl4[i] = ((const u32x4*)wfrag)[i];
    __syncthreads();

    int wid = (blockIdx.x * 256 + tid) >> 6;
    if (wid >= NNODES / 16) return;        // 3125 waves
    int lane = tid & 63;
    int node0 = wid * 16;
    int row = node0 + (lane & 15);
    int khi = (lane >> 4) << 3;            // 0,8,16,24

    f32x4 acc[4];
#pragma unroll
    for (int nb = 0; nb < 4; ++nb) acc[nb] = (f32x4){0.f, 0.f, 0.f, 0.f};

    const float* xr = x + (size_t)row * NFEAT + khi;
#pragma unroll 4
    for (int kb = 0; kb < 16; ++kb) {
        float4 xa = *(const float4*)(xr);
        float4 xb = *(const float4*)(xr + 4);
        xr += 32;
        s16x8 a;
        a[0] = (short)f2bf(xa.x); a[1] = (short)f2bf(xa.y);
        a[2] = (short)f2bf(xa.z); a[3] = (short)f2bf(xa.w);
        a[4] = (short)f2bf(xb.x); a[5] = (short)f2bf(xb.y);
        a[6] = (short)f2bf(xb.z); a[7] = (short)f2bf(xb.w);
#pragma unroll
        for (int nb = 0; nb < 4; ++nb) {
            s16x8 bb = *(const s16x8*)(&wl[(size_t)((kb * 4 + nb) * 64 + lane) * 8]);
            acc[nb] = __builtin_amdgcn_mfma_f32_16x16x32_bf16(a, bb, acc[nb], 0, 0, 0);
        }
    }

    int chi = lane >> 4;
#pragma unroll
    for (int nb = 0; nb < 4; ++nb) {
        int col = nb * 16 + (lane & 15);
        float bias = b[col];
#pragma unroll
        for (int r = 0; r < 4; ++r) {
            int n = node0 + chi * 4 + r;
            h0[(size_t)n * NHID + col] = f2bf(acc[nb][r] + bias);
        }
    }
}

// ---------------- SpMM (unified rows, 8 edges in flight) ----------------

__device__ __forceinline__ void acc_edge(float* acc, u32x4 g, float wgt) {
    acc[0] = fmaf(wgt, bflo(g[0]), acc[0]);
    acc[1] = fmaf(wgt, bfhi(g[0]), acc[1]);
    acc[2] = fmaf(wgt, bflo(g[1]), acc[2]);
    acc[3] = fmaf(wgt, bfhi(g[1]), acc[3]);
    acc[4] = fmaf(wgt, bflo(g[2]), acc[4]);
    acc[5] = fmaf(wgt, bfhi(g[2]), acc[5]);
    acc[6] = fmaf(wgt, bflo(g[3]), acc[6]);
    acc[7] = fmaf(wgt, bfhi(g[3]), acc[7]);
}

// 8 nodes/wave, 8 lanes x uint4 (8 bf16 feats) per node.
__global__ __launch_bounds__(256) void spmm_pull_kernel(
        const uint32* __restrict__ edata, const int* __restrict__ row_ptr,
        const bf16_t* __restrict__ h_cur, const bf16_t* __restrict__ h0,
        bf16_t* __restrict__ h_next) {
    int gid = blockIdx.x * blockDim.x + threadIdx.x;
    int wave = gid >> 6;
    int lane = threadIdx.x & 63;
    int grp = lane >> 3;            // 0..7
    int fl = (lane & 7) << 3;       // feature base (8 bf16 = 16 B)
    int node = wave * 8 + grp;
    int beg = 0, deg = 0;
    if (node < NNODES) {
        beg = row_ptr[node];
        deg = row_ptr[node + 1] - beg;
    }
    int steps = deg;
    steps = max(steps, __shfl_xor(steps, 8));
    steps = max(steps, __shfl_xor(steps, 16));
    steps = max(steps, __shfl_xor(steps, 32));

    float acc[8];
#pragma unroll
    for (int j = 0; j < 8; ++j) acc[j] = 0.f;

    int t = 0;
    for (; t + 7 < steps; t += 8) {
        uint32 e[8];
        float w[8];
        u32x4 g[8];
#pragma unroll
        for (int u = 0; u < 8; ++u) {
            bool v = (t + u < deg);
            e[u] = edata[v ? (beg + t + u) : 0];
            w[u] = v ? bfhi(e[u]) : 0.f;
        }
#pragma unroll
        for (int u = 0; u < 8; ++u)
            g[u] = *(const u32x4*)(h_cur + ((size_t)(e[u] & 0xFFFFu) << 6) + fl);
#pragma unroll
        for (int u = 0; u < 8; ++u)
            acc_edge(acc, g[u], w[u]);
    }
    for (; t + 3 < steps; t += 4) {
        uint32 e[4];
        float w[4];
        u32x4 g[4];
#pragma unroll
        for (int u = 0; u < 4; ++u) {
            bool v = (t + u < deg);
            e[u] = edata[v ? (beg + t + u) : 0];
            w[u] = v ? bfhi(e[u]) : 0.f;
        }
#pragma unroll
        for (int u = 0; u < 4; ++u)
            g[u] = *(const u32x4*)(h_cur + ((size_t)(e[u] & 0xFFFFu) << 6) + fl);
#pragma unroll
        for (int u = 0; u < 4; ++u)
            acc_edge(acc, g[u], w[u]);
    }
    for (; t < steps; ++t) {
        bool v = (t < deg);
        uint32 e0 = edata[v ? (beg + t) : 0];
        float w0 = v ? bfhi(e0) : 0.f;
        u32x4 g0 = *(const u32x4*)(h_cur + ((size_t)(e0 & 0xFFFFu) << 6) + fl);
        acc_edge(acc, g0, w0);
    }

    if (node < NNODES) {
        size_t o = ((size_t)node << 6) + fl;
        u32x4 hv = *(const u32x4*)(h0 + o);
        const float s = 1.0f - ALPHA;
        float r[8];
        r[0] = fmaf(s, bflo(hv[0]), acc[0]);
        r[1] = fmaf(s, bfhi(hv[0]), acc[1]);
        r[2] = fmaf(s, bflo(hv[1]), acc[2]);
        r[3] = fmaf(s, bfhi(hv[1]), acc[3]);
        r[4] = fmaf(s, bflo(hv[2]), acc[4]);
        r[5] = fmaf(s, bfhi(hv[2]), acc[5]);
        r[6] = fmaf(s, bflo(hv[3]), acc[6]);
        r[7] = fmaf(s, bfhi(hv[3]), acc[7]);
        u32x4 ov;
        ov[0] = (uint32)f2bf(r[0]) | ((uint32)f2bf(r[1]) << 16);
        ov[1] = (uint32)f2bf(r[2]) | ((uint32)f2bf(r[3]) << 16);
        ov[2] = (uint32)f2bf(r[4]) | ((uint32)f2bf(r[5]) << 16);
        ov[3] = (uint32)f2bf(r[6]) | ((uint32)f2bf(r[7]) << 16);
        *(u32x4*)(h_next + o) = ov;
    }
}

// ---------------- linear_out ----------------

__global__ __launch_bounds__(256) void linear_out_kernel(
        const bf16_t* __restrict__ h, const float* __restrict__ W,
        const float* __restrict__ b, float* __restrict__ out) {
    __shared__ float wsh[NHID * NCLASSES];
    __shared__ float bs[NCLASSES];
    int tid = threadIdx.x;
    for (int i = tid; i < NHID * NCLASSES; i += 256) wsh[i] = W[i];
    if (tid < NCLASSES) bs[tid] = b[tid];
    __syncthreads();
    int node = blockIdx.x * 256 + tid;
    if (node >= NNODES) return;
    float acc[NCLASSES];
#pragma unroll
    for (int c = 0; c < NCLASSES; ++c) acc[c] = bs[c];
    const bf16_t* hr = h + (size_t)node * NHID;
#pragma unroll
    for (int q = 0; q < 8; ++q) {
        u32x4 v = *(const u32x4*)(hr + q * 8);
        float hv[8];
        hv[0] = bflo(v[0]); hv[1] = bfhi(v[0]);
        hv[2] = bflo(v[1]); hv[3] = bfhi(v[1]);
        hv[4] = bflo(v[2]); hv[5] = bfhi(v[2]);
        hv[6] = bflo(v[3]); hv[7] = bfhi(v[3]);
#pragma unroll
        for (int kk = 0; kk < 8; ++kk) {
#pragma unroll
            for (int c = 0; c < NCLASSES; ++c)
                acc[c] = fmaf(hv[kk], wsh[(q * 8 + kk) * NCLASSES + c], acc[c]);
        }
    }
    float* op = out + (size_t)node * NCLASSES;
#pragma unroll
    for (int c = 0; c < NCLASSES; c += 4)
        *(float4*)(op + c) = make_float4(acc[c], acc[c + 1], acc[c + 2], acc[c + 3]);
}

extern "C" void kernel_launch(void* const* d_in, const int* in_sizes, int n_in,
                              void* d_out, int out_size, void* d_ws, size_t ws_size,
                              hipStream_t stream) {
    const float* x     = (const float*)d_in[0];
    const int*   ei    = (const int*)d_in[1];
    const float* ew    = (const float*)d_in[2];
    const float* W_in  = (const float*)d_in[3];
    const float* b_in  = (const float*)d_in[4];
    const float* W_out = (const float*)d_in[5];
    const float* b_out = (const float*)d_in[6];
    float* out = (float*)d_out;

    const int HN = NNODES * NHID;            // 3.2M elements
    bf16_t* h0 = (bf16_t*)d_ws;              // 6.4 MB each
    bf16_t* ha = h0 + HN;
    bf16_t* hb = ha + HN;
    bf16_t* wfrag = hb + HN;                 // 64 KB
    uint32* edata  = (uint32*)(wfrag + NFEAT * NHID);   // 3.2 MB packed
    int* row_ptr = (int*)(edata + NEDGES);   // NNODES+1
    int* cursor  = row_ptr + (NNODES + 1);
    int* counts  = cursor + NNODES;
    int* bsum    = counts + NNODES;
    int* boff    = bsum + 64;

    const int* src = ei;
    const int* dst = ei + NEDGES;

    // ---- CSR build (packed 4B edges) ----
    hipMemsetAsync(counts, 0, NNODES * sizeof(int), stream);
    hist_kernel<<<(NEDGES + 255) / 256, 256, 0, stream>>>(dst, counts);
    const int NB = (NNODES + 1023) / 1024;
    scan1_kernel<<<NB, 1024, 0, stream>>>(counts, row_ptr, bsum);
    scan2_kernel<<<1, 64, 0, stream>>>(bsum, boff);
    scan3_kernel<<<(NNODES + 256) / 256, 256, 0, stream>>>(boff, row_ptr, cursor);
    csr_scatter_kernel<<<(NEDGES + 255) / 256, 256, 0, stream>>>(src, dst, ew, cursor, edata);

    // ---- h0 = bf16(x @ W_in + b_in), via MFMA ----
    prep_w_kernel<<<(NFEAT * NHID + 255) / 256, 256, 0, stream>>>(W_in, wfrag);
    const int GEMM_BLOCKS = (NNODES / 16 + 3) / 4;   // 782
    linear_in_kernel<<<GEMM_BLOCKS, 256, 0, stream>>>(x, wfrag, b_in, h0);

    // ---- 10 APPNP layers ----
    const int NWAVES = (NNODES + 7) / 8;                 // 6250
    const int SPMM_BLOCKS = (NWAVES * 64 + 255) / 256;   // 1563
    bf16_t* cur = h0;
    bf16_t* nxt = ha;
    for (int l = 0; l < NLAYERS; ++l) {
        spmm_pull_kernel<<<SPMM_BLOCKS, 256, 0, stream>>>(edata, row_ptr, cur, h0, nxt);
        cur = nxt;
        nxt = (cur == ha) ? hb : ha;
    }

    // ---- out = cur @ W_out + b_out ----
    linear_out_kernel<<<(NNODES + 255) / 256, 256, 0, stream>>>(cur, W_out, b_out, out);
}